// Round 5
// baseline (160.130 us; speedup 1.0000x reference)
//
#include <hip/hip_runtime.h>
#include <stdint.h>

#define NIN 1024
#define NMID 256
#define NOUT 64
#define BM 64

typedef __attribute__((ext_vector_type(8))) short bf16x8;
typedef __attribute__((ext_vector_type(4))) float fx4;
typedef __attribute__((ext_vector_type(16))) float f32x16;
typedef __attribute__((ext_vector_type(4))) uint32_t u32x4;

union FragU { bf16x8 v; uint32_t u[4]; };

static __device__ __forceinline__ uint32_t cvtpk(float lo, float hi) {
  uint32_t r;
  asm("v_cvt_pk_bf16_f32 %0, %1, %2" : "=v"(r) : "v"(lo), "v"(hi));
  return r;
}

// ---- kernel 1: W1 -> MFMA-fragment-ready bf16 layout, W2 -> bf16 rowmajor ----
// w1f element addr = (c*4096 + kb*32 + r)*8 + e  where n = c*32+r, k = kb*8+e.
__global__ __launch_bounds__(256) void cvt_weights(
    const float* __restrict__ W1, const float* __restrict__ W2,
    unsigned short* __restrict__ w1f, unsigned short* __restrict__ w2b) {
  int gid = blockIdx.x * 256 + threadIdx.x;
  if (gid < 32768) {                      // 8 c * 128 kb * 32 r
    int r = gid & 31;
    int kb = (gid >> 5) & 127;
    int c = gid >> 12;
    const float* s = W1 + (size_t)(c * 32 + r) * NIN + kb * 8;
    fx4 v0 = *(const fx4*)s;
    fx4 v1 = *(const fx4*)(s + 4);
    u32x4 o = {cvtpk(v0.x, v0.y), cvtpk(v0.z, v0.w),
               cvtpk(v1.x, v1.y), cvtpk(v1.z, v1.w)};
    *(u32x4*)(w1f + (size_t)gid * 8) = o;
  } else {
    int e2 = (gid - 32768) << 2;
    if (e2 < NOUT * NMID) {
      fx4 v = *(const fx4*)(W2 + e2);
      uint2 p; p.x = cvtpk(v.x, v.y); p.y = cvtpk(v.z, v.w);
      *(uint2*)(w2b + e2) = p;
    }
  }
}

// ---- kernel 2: fused MLP, barrier-free layer-1 streaming ----
// 256 thr = 4 waves (wn 0..3 = col quarter). BM=64 batch rows/block.
// A-frags loaded DIRECTLY from global x (fp32, per-lane 32B contiguous,
// lane l & l+32 complete each 64B line); B-frags from frag-ready w1f (L2).
// No LDS, no barriers in the K-loop. LDS only for the 32KB h handoff.
__global__ __launch_bounds__(256, 3) void livenet_main(
    const float* __restrict__ x,
    const unsigned short* __restrict__ w1f,
    const float* __restrict__ b1,
    const unsigned short* __restrict__ w2b,
    const float* __restrict__ b2,
    float* __restrict__ y) {

  __shared__ __align__(16) char smem[32768];  // h [64 rows][512B] XOR-swizzled

  const int tid = threadIdx.x;
  const int lane = tid & 63;
  const int w = tid >> 6;      // wave 0..3 = wn (col quarter)
  const int wn = w;
  const int l31 = lane & 31;
  const int lh = lane >> 5;    // k-half within fragment
  const int row0 = blockIdx.x * BM;

  f32x16 acc[2][2];
#pragma unroll
  for (int mt = 0; mt < 2; ++mt)
#pragma unroll
    for (int nt = 0; nt < 2; ++nt)
#pragma unroll
      for (int q = 0; q < 16; ++q) acc[mt][nt][q] = 0.f;

  // B fragment bases: c = wn*2 + nt
  const unsigned short* wf0 = w1f + ((size_t)(wn * 2 + 0) * 4096 + l31) * 8;
  const unsigned short* wf1 = w1f + ((size_t)(wn * 2 + 1) * 4096 + l31) * 8;

  // A fragment row bases (global fp32)
  const float* xr0 = x + (size_t)(row0 + l31) * NIN;        // mt=0
  const float* xr1 = x + (size_t)(row0 + 32 + l31) * NIN;   // mt=1

  for (int t = 0; t < 16; ++t) {
    // B frags: 8 fully-coalesced 16B loads from L2-hot w1f
    bf16x8 bfr[2][4];
#pragma unroll
    for (int kk = 0; kk < 4; ++kk) {
      uint32_t kb = (uint32_t)(t * 8 + kk * 2 + lh);
      bfr[0][kk] = *(const bf16x8*)(wf0 + kb * 256u);
      bfr[1][kk] = *(const bf16x8*)(wf1 + kb * 256u);
    }

#pragma unroll
    for (int kk = 0; kk < 4; ++kk) {
      const int kof = t * 64 + (kk * 2 + lh) * 8;  // float index
      fx4 va = *(const fx4*)(xr0 + kof);
      fx4 vb = *(const fx4*)(xr0 + kof + 4);
      fx4 vc = *(const fx4*)(xr1 + kof);
      fx4 vd = *(const fx4*)(xr1 + kof + 4);
      FragU f, g;
      f.u[0] = cvtpk(va.x, va.y); f.u[1] = cvtpk(va.z, va.w);
      f.u[2] = cvtpk(vb.x, vb.y); f.u[3] = cvtpk(vb.z, vb.w);
      g.u[0] = cvtpk(vc.x, vc.y); g.u[1] = cvtpk(vc.z, vc.w);
      g.u[2] = cvtpk(vd.x, vd.y); g.u[3] = cvtpk(vd.z, vd.w);
      __builtin_amdgcn_s_setprio(1);
      acc[0][0] = __builtin_amdgcn_mfma_f32_32x32x16_bf16(f.v, bfr[0][kk], acc[0][0], 0, 0, 0);
      acc[0][1] = __builtin_amdgcn_mfma_f32_32x32x16_bf16(f.v, bfr[1][kk], acc[0][1], 0, 0, 0);
      acc[1][0] = __builtin_amdgcn_mfma_f32_32x32x16_bf16(g.v, bfr[0][kk], acc[1][0], 0, 0, 0);
      acc[1][1] = __builtin_amdgcn_mfma_f32_32x32x16_bf16(g.v, bfr[1][kk], acc[1][1], 0, 0, 0);
      __builtin_amdgcn_s_setprio(0);
    }
  }

  // ---- layer-1 epilogue: bias+relu -> h bf16 [64][256] (32-chunk XOR) ----
  float b1v[2];
#pragma unroll
  for (int nt = 0; nt < 2; ++nt) b1v[nt] = b1[wn * 64 + nt * 32 + l31];

#pragma unroll
  for (int mt = 0; mt < 2; ++mt) {
#pragma unroll
    for (int nt = 0; nt < 2; ++nt) {
      int col = wn * 64 + nt * 32 + l31;
#pragma unroll
      for (int rg = 0; rg < 16; ++rg) {
        int row = mt * 32 + (rg & 3) + 8 * (rg >> 2) + 4 * lh;
        float v = acc[mt][nt][rg] + b1v[nt];
        v = v > 0.f ? v : 0.f;
        int j = (col >> 3) ^ (row & 31);
        *(unsigned short*)(smem + row * 512 + (j << 4) + (col & 7) * 2) =
            (unsigned short)cvtpk(v, v);
      }
    }
  }
  __syncthreads();

  // ---- layer 2: y[64][64] = relu(h @ W2^T + b2) ----
  f32x16 acc2;
#pragma unroll
  for (int q = 0; q < 16; ++q) acc2[q] = 0.f;

  const int r2 = (w >> 1) * 32;
  const int c2 = (w & 1) * 32;
  const int arow = r2 + l31;
  const uint32_t arx = (uint32_t)(arow & 31);
  const unsigned short* w2row = w2b + (size_t)(c2 + l31) * NMID + lh * 8;

#pragma unroll
  for (int kk = 0; kk < 16; ++kk) {
    bf16x8 a2 = *(const bf16x8*)(smem + arow * 512 +
                                 ((((uint32_t)(kk * 2 + lh)) ^ arx) << 4));
    bf16x8 bw = *(const bf16x8*)(w2row + kk * 16);
    acc2 = __builtin_amdgcn_mfma_f32_32x32x16_bf16(a2, bw, acc2, 0, 0, 0);
  }

  float bias2 = b2[c2 + l31];
#pragma unroll
  for (int rg = 0; rg < 16; ++rg) {
    int row = r2 + (rg & 3) + 8 * (rg >> 2) + 4 * lh;
    float v = acc2[rg] + bias2;
    v = v > 0.f ? v : 0.f;
    y[(size_t)(row0 + row) * NOUT + c2 + l31] = v;
  }
}

extern "C" void kernel_launch(void* const* d_in, const int* in_sizes, int n_in,
                              void* d_out, int out_size, void* d_ws, size_t ws_size,
                              hipStream_t stream) {
  const float* x  = (const float*)d_in[0];
  const float* W1 = (const float*)d_in[1];
  const float* b1 = (const float*)d_in[2];
  const float* W2 = (const float*)d_in[3];
  const float* b2 = (const float*)d_in[4];
  float* y = (float*)d_out;

  unsigned short* w1f = (unsigned short*)d_ws;            // 512 KB frag-layout
  unsigned short* w2b = w1f + (size_t)NMID * NIN;         // 32 KB rowmajor

  const int batch = in_sizes[0] / NIN;

  hipLaunchKernelGGL(cvt_weights, dim3(144), dim3(256), 0, stream,
                     W1, W2, w1f, w2b);
  hipLaunchKernelGGL(livenet_main, dim3(batch / BM), dim3(256), 0, stream,
                     x, w1f, b1, w2b, b2, y);
}

// Round 6
// 82.897 us; speedup vs baseline: 1.9317x; 1.9317x over previous
//
#include <hip/hip_runtime.h>
#include <stdint.h>

#define NIN 1024
#define NMID 256
#define NOUT 64
#define BM 64
#define BK 64

typedef __attribute__((ext_vector_type(8))) short bf16x8;
typedef __attribute__((ext_vector_type(4))) float fx4;
typedef __attribute__((ext_vector_type(16))) float f32x16;
typedef __attribute__((ext_vector_type(4))) uint32_t u32x4;

#define XS_TILE 16384   // [64 rows][256B fp32], 16-chunk XOR swizzle per row
#define LDS_SZ  32768   // 2 x-tile buffers; h [64][512B] overlays after loop

union FragU { bf16x8 v; uint32_t u[4]; };

static __device__ __forceinline__ uint32_t cvtpk(float lo, float hi) {
  uint32_t r;
  asm("v_cvt_pk_bf16_f32 %0, %1, %2" : "=v"(r) : "v"(lo), "v"(hi));
  return r;
}
static __device__ __forceinline__ void gload16(const void* g, void* l) {
  __builtin_amdgcn_global_load_lds(
      (const __attribute__((address_space(1))) uint32_t*)g,
      (__attribute__((address_space(3))) uint32_t*)l, 16, 0, 0);
}

#define VMCNT4() asm volatile("s_waitcnt vmcnt(4)" ::: "memory")
#define VMCNT0() asm volatile("s_waitcnt vmcnt(0)" ::: "memory")
#define LGKM0()  asm volatile("s_waitcnt lgkmcnt(0)" ::: "memory")
#define SBAR()   __builtin_amdgcn_s_barrier()
#define SFENCE() __builtin_amdgcn_sched_barrier(0)

// ---- kernel 1: W1 -> MFMA-fragment-ready bf16 layout, W2 -> bf16 rowmajor ----
// w1f element addr = (c*4096 + kb*32 + r)*8 + e  where n = c*32+r, k = kb*8+e.
__global__ __launch_bounds__(256) void cvt_weights(
    const float* __restrict__ W1, const float* __restrict__ W2,
    unsigned short* __restrict__ w1f, unsigned short* __restrict__ w2b) {
  int gid = blockIdx.x * 256 + threadIdx.x;
  if (gid < 32768) {                      // 8 c * 128 kb * 32 r
    int r = gid & 31;
    int kb = (gid >> 5) & 127;
    int c = gid >> 12;
    const float* s = W1 + (size_t)(c * 32 + r) * NIN + kb * 8;
    fx4 v0 = *(const fx4*)s;
    fx4 v1 = *(const fx4*)(s + 4);
    u32x4 o = {cvtpk(v0.x, v0.y), cvtpk(v0.z, v0.w),
               cvtpk(v1.x, v1.y), cvtpk(v1.z, v1.w)};
    *(u32x4*)(w1f + (size_t)gid * 8) = o;
  } else {
    int e2 = (gid - 32768) << 2;
    if (e2 < NOUT * NMID) {
      fx4 v = *(const fx4*)(W2 + e2);
      uint2 p; p.x = cvtpk(v.x, v.y); p.y = cvtpk(v.z, v.w);
      *(uint2*)(w2b + e2) = p;
    }
  }
}

// ---- kernel 2: fused MLP, depth-2 counted-vmcnt pipeline, lean LDS ----
// 256 thr = 4 waves (wn = col quarter), BM=64 rows/block.
// x: fp32 -> LDS via global_load_lds (linear dest, inverse-swizzled coalesced
//    src), double-buffered, depth-2 prefetch, NEVER vmcnt(0) mid-loop.
// W1: fragment-ready bf16 from L2 (no LDS). h handoff overlays x buffers.
__global__ __launch_bounds__(256, 3) void livenet_main(
    const float* __restrict__ x,
    const unsigned short* __restrict__ w1f,
    const float* __restrict__ b1,
    const unsigned short* __restrict__ w2b,
    const float* __restrict__ b2,
    float* __restrict__ y) {

  extern __shared__ __align__(16) char smem[];

  const int tid = threadIdx.x;
  const int lane = tid & 63;
  const int w = tid >> 6;      // wave 0..3 = wn
  const int wn = w;
  const int l31 = lane & 31;
  const int l15 = lane & 15;
  const int lh = lane >> 5;
  const int row0 = blockIdx.x * BM;

  // x staging: 4 chunks/thread; linear LDS dest, inverse-swizzled global src
  uint32_t xsrc[4], xdst[4];
#pragma unroll
  for (int i = 0; i < 4; ++i) {
    uint32_t o = (uint32_t)(i * 4096 + tid * 16);
    uint32_t r = o >> 8;              // row (256B rows), 0..63
    uint32_t pc = (o >> 4) & 15u;     // physical 16B chunk
    uint32_t j = pc ^ (r & 15u);      // logical chunk
    xsrc[i] = (uint32_t)(row0 + (int)r) * NIN + j * 4u;  // float elems
    xdst[i] = o;
  }

#define XSTAGE(pbuf, k0)                                        \
  { char* xb_ = smem + (pbuf) * XS_TILE;                        \
    _Pragma("unroll") for (int i_ = 0; i_ < 4; ++i_)            \
      gload16(x + xsrc[i_] + (k0), xb_ + xdst[i_]); }

  f32x16 acc[2][2];
#pragma unroll
  for (int mt = 0; mt < 2; ++mt)
#pragma unroll
    for (int nt = 0; nt < 2; ++nt)
#pragma unroll
      for (int q = 0; q < 16; ++q) acc[mt][nt][q] = 0.f;

  // B fragment bases: c = wn*2 + nt
  const unsigned short* wf0 = w1f + ((size_t)(wn * 2 + 0) * 4096 + l31) * 8;
  const unsigned short* wf1 = w1f + ((size_t)(wn * 2 + 1) * 4096 + l31) * 8;

  // A fragment row bases in LDS (fp32, 256B rows)
  const uint32_t ar0 = (uint32_t)(l31) * 256u;        // mt=0 rows 0..31
  const uint32_t ar1 = (uint32_t)(32 + l31) * 256u;   // mt=1 rows 32..63

  // prologue: stage tiles 0 and 1 (8 loads outstanding)
  XSTAGE(0, 0);
  XSTAGE(1, BK);

  for (int t = 0; t < 16; ++t) {
    // tile t's 4 loads are the oldest; t+1's (if any) stay in flight
    if (t < 15) { VMCNT4(); } else { VMCNT0(); }
    SBAR();
    SFENCE();

    const char* xb = smem + (t & 1) * XS_TILE;

    // B frags: 8 fully-coalesced 16B loads from L2-hot w1f
    bf16x8 bfr[2][4];
#pragma unroll
    for (int kk = 0; kk < 4; ++kk) {
      uint32_t kb = (uint32_t)(t * 8 + kk * 2 + lh);
      bfr[0][kk] = *(const bf16x8*)(wf0 + kb * 256u);
      bfr[1][kk] = *(const bf16x8*)(wf1 + kb * 256u);
    }

#pragma unroll
    for (int kk = 0; kk < 4; ++kk) {
      uint32_t j0 = (uint32_t)(kk * 4 + lh * 2);
      fx4 va = *(const fx4*)(xb + ar0 + ((j0 ^ (uint32_t)l15) << 4));
      fx4 vb = *(const fx4*)(xb + ar0 + (((j0 + 1) ^ (uint32_t)l15) << 4));
      fx4 vc = *(const fx4*)(xb + ar1 + ((j0 ^ (uint32_t)l15) << 4));
      fx4 vd = *(const fx4*)(xb + ar1 + (((j0 + 1) ^ (uint32_t)l15) << 4));
      FragU f, g;
      f.u[0] = cvtpk(va.x, va.y); f.u[1] = cvtpk(va.z, va.w);
      f.u[2] = cvtpk(vb.x, vb.y); f.u[3] = cvtpk(vb.z, vb.w);
      g.u[0] = cvtpk(vc.x, vc.y); g.u[1] = cvtpk(vc.z, vc.w);
      g.u[2] = cvtpk(vd.x, vd.y); g.u[3] = cvtpk(vd.z, vd.w);
      __builtin_amdgcn_s_setprio(1);
      acc[0][0] = __builtin_amdgcn_mfma_f32_32x32x16_bf16(f.v, bfr[0][kk], acc[0][0], 0, 0, 0);
      acc[0][1] = __builtin_amdgcn_mfma_f32_32x32x16_bf16(f.v, bfr[1][kk], acc[0][1], 0, 0, 0);
      acc[1][0] = __builtin_amdgcn_mfma_f32_32x32x16_bf16(g.v, bfr[0][kk], acc[1][0], 0, 0, 0);
      acc[1][1] = __builtin_amdgcn_mfma_f32_32x32x16_bf16(g.v, bfr[1][kk], acc[1][1], 0, 0, 0);
      __builtin_amdgcn_s_setprio(0);
    }

    LGKM0();   // this wave's ds_reads complete before others may overwrite
    SBAR();
    SFENCE();
    if (t + 2 < 16) XSTAGE(t & 1, (t + 2) * BK);
  }

  // ---- layer-1 epilogue: bias+relu -> h bf16 [64][256] (32-chunk XOR) ----
  float b1v[2];
#pragma unroll
  for (int nt = 0; nt < 2; ++nt) b1v[nt] = b1[wn * 64 + nt * 32 + l31];

#pragma unroll
  for (int mt = 0; mt < 2; ++mt) {
#pragma unroll
    for (int nt = 0; nt < 2; ++nt) {
      int col = wn * 64 + nt * 32 + l31;
#pragma unroll
      for (int rg = 0; rg < 16; ++rg) {
        int row = mt * 32 + (rg & 3) + 8 * (rg >> 2) + 4 * lh;
        float v = acc[mt][nt][rg] + b1v[nt];
        v = v > 0.f ? v : 0.f;
        int j = (col >> 3) ^ (row & 31);
        *(unsigned short*)(smem + row * 512 + (j << 4) + (col & 7) * 2) =
            (unsigned short)cvtpk(v, v);
      }
    }
  }
  __syncthreads();

  // ---- layer 2: y[64][64] = relu(h @ W2^T + b2) ----
  f32x16 acc2;
#pragma unroll
  for (int q = 0; q < 16; ++q) acc2[q] = 0.f;

  const int r2 = (w >> 1) * 32;
  const int c2 = (w & 1) * 32;
  const int arow = r2 + l31;
  const uint32_t arx = (uint32_t)(arow & 31);
  const unsigned short* w2row = w2b + (size_t)(c2 + l31) * NMID + lh * 8;

#pragma unroll
  for (int kk = 0; kk < 16; ++kk) {
    bf16x8 a2 = *(const bf16x8*)(smem + arow * 512 +
                                 ((((uint32_t)(kk * 2 + lh)) ^ arx) << 4));
    bf16x8 bw = *(const bf16x8*)(w2row + kk * 16);
    acc2 = __builtin_amdgcn_mfma_f32_32x32x16_bf16(a2, bw, acc2, 0, 0, 0);
  }

  float bias2 = b2[c2 + l31];
#pragma unroll
  for (int rg = 0; rg < 16; ++rg) {
    int row = r2 + (rg & 3) + 8 * (rg >> 2) + 4 * lh;
    float v = acc2[rg] + bias2;
    v = v > 0.f ? v : 0.f;
    y[(size_t)(row0 + row) * NOUT + c2 + l31] = v;
  }
}

extern "C" void kernel_launch(void* const* d_in, const int* in_sizes, int n_in,
                              void* d_out, int out_size, void* d_ws, size_t ws_size,
                              hipStream_t stream) {
  const float* x  = (const float*)d_in[0];
  const float* W1 = (const float*)d_in[1];
  const float* b1 = (const float*)d_in[2];
  const float* W2 = (const float*)d_in[3];
  const float* b2 = (const float*)d_in[4];
  float* y = (float*)d_out;

  unsigned short* w1f = (unsigned short*)d_ws;            // 512 KB frag-layout
  unsigned short* w2b = w1f + (size_t)NMID * NIN;         // 32 KB rowmajor

  const int batch = in_sizes[0] / NIN;

  hipLaunchKernelGGL(cvt_weights, dim3(144), dim3(256), 0, stream,
                     W1, W2, w1f, w2b);

  static int lds_set = 0;
  if (!lds_set) {
    hipFuncSetAttribute((const void*)livenet_main,
                        hipFuncAttributeMaxDynamicSharedMemorySize, LDS_SZ);
    lds_set = 1;
  }
  hipLaunchKernelGGL(livenet_main, dim3(batch / BM), dim3(256), LDS_SZ, stream,
                     x, w1f, b1, w2b, b2, y);
}